// Round 2
// baseline (1356.086 us; speedup 1.0000x reference)
//
#include <hip/hip_runtime.h>
#include <hip/hip_bf16.h>

#define Hn   89
#define Tn   120
#define BMn  64
#define LDP  104   // LDS row pitch (bf16 elems): 208B = 52 dwords -> balanced bank rotation
#define NTHR 384   // 6 waves: one per 16-wide j-slice of the 96-padded hidden dim

using bf16   = __bf16;
using bf16x2 = __attribute__((ext_vector_type(2))) __bf16;
using bf16x8 = __attribute__((ext_vector_type(8))) __bf16;
using f32x4  = __attribute__((ext_vector_type(4))) float;

__device__ __forceinline__ float fsig(float x) {
#if __has_builtin(__builtin_amdgcn_exp2f) && __has_builtin(__builtin_amdgcn_rcpf)
  return __builtin_amdgcn_rcpf(1.f + __builtin_amdgcn_exp2f(-1.44269504f * x));
#else
  return 1.f / (1.f + exp2f(-1.44269504f * x));
#endif
}
__device__ __forceinline__ float ftanh(float x) {
#if __has_builtin(__builtin_amdgcn_exp2f) && __has_builtin(__builtin_amdgcn_rcpf)
  return 1.f - 2.f * __builtin_amdgcn_rcpf(1.f + __builtin_amdgcn_exp2f(2.88539008f * x));
#else
  return 1.f - 2.f / (1.f + exp2f(2.88539008f * x));
#endif
}

// Persistent block: 64 batch rows x 120 steps. Wave w owns j-slice [16w,16w+16);
// weights live in registers as MFMA B-frags. ONE barrier per step:
//   { write H(t),X(t) -> buf[t&1]; issue X(t+1); BAR; read buf[t&1]; MFMA+gates }
// Fast waves then write buf[(t+1)&1] which slow readers of buf[t&1] never touch.
// Biases folded into k=89 constant-1.0 column; r/z i+h accs merged.
__global__ __launch_bounds__(NTHR, 3)
void gru_fused(const float* __restrict__ X,    // [B][T][89]
               const float* __restrict__ Wih,  // [267][89]
               const float* __restrict__ Whh,  // [267][89]
               const float* __restrict__ bih,  // [267]
               const float* __restrict__ bhh,  // [267]
               const float* __restrict__ Wm,   // [32][89]
               const float* __restrict__ bm,   // [32]
               const float* __restrict__ Wo,   // [32]
               const float* __restrict__ bo,   // [1]
               float* __restrict__ Y,          // [B] mscore | [B][32] mmetric
               int Bt)
{
  __shared__ __align__(16) bf16 Xl[2][BMn][LDP];
  __shared__ __align__(16) bf16 Hl[2][BMn][LDP];
  __shared__ float Ml[BMn][32];

  const int tid  = threadIdx.x;
  const int lane = tid & 63;
  const int wv   = tid >> 6;       // 0..5 = j-tile
  const int l15  = lane & 15;
  const int kg   = lane >> 4;      // 0..3
  const int j    = wv * 16 + l15;  // 0..95
  const bool jok = (j < Hn);       // j==89 is the constant-1 column, 90..95 pad
  const size_t brow0 = (size_t)blockIdx.x * BMn;

  // ---- weights -> persistent register B-frags; k==89 row carries biases ----
  bf16x8 Bf[3][2][3];  // [gate r/z/n][ih/hh][k-tile]
#pragma unroll
  for (int g = 0; g < 3; ++g)
#pragma unroll
    for (int s = 0; s < 2; ++s) {
      const float* W = s ? Whh : Wih;
#pragma unroll
      for (int kt = 0; kt < 3; ++kt) {
        bf16x8 f;
        const int k0 = kt * 32 + kg * 8;
#pragma unroll
        for (int e = 0; e < 8; ++e) {
          const int k = k0 + e;
          float v = 0.f;
          if (jok) {
            if (k < Hn) v = W[(size_t)(g * Hn + j) * Hn + k];
            else if (k == Hn) {           // bias column (pairs with 1.0 in X/H col 89)
              if (g < 2)      v = s ? 0.f : (bih[g * Hn + j] + bhh[g * Hn + j]);
              else            v = s ? bhh[2 * Hn + j] : bih[2 * Hn + j];
            }
          }
          f[e] = (bf16)v;
        }
        Bf[g][s][kt] = f;
      }
    }

  // ---- X prefetch slots: 64 rows x 45 chunks (44 pairs + {x[88],1.0}) ----
  int soff[8], loff[8];
  bool valid[8], last[8];
#pragma unroll
  for (int i = 0; i < 8; ++i) {
    const int p = tid + i * NTHR;        // 0..3071; 2880 used
    const int r = p / 45, s = p - r * 45;
    valid[i] = (p < BMn * 45);
    last[i]  = (s == 44);
    soff[i]  = r * (Tn * Hn) + s * 2;
    loff[i]  = r * LDP + s * 2;
  }
  const float* Xb2 = X + brow0 * (size_t)Tn * Hn;
  float pa[8], pb[8];
  int tH = 0;

  auto issue = [&](int tHv) {
#pragma unroll
    for (int i = 0; i < 8; ++i) {
      if (valid[i]) {
        pa[i] = Xb2[soff[i] + tHv];
        pb[i] = last[i] ? 1.0f : Xb2[soff[i] + 1 + tHv];
      }
    }
  };

  issue(0);

  // init pad region: X cols 90..103 = 0 (both bufs); H col89 = 1.0, 90..103 = 0
  for (int i = tid; i < BMn; i += NTHR) {
#pragma unroll
    for (int b = 0; b < 2; ++b) {
      for (int c = 90; c < LDP; ++c) Xl[b][i][c] = (bf16)0.f;
      Hl[b][i][89] = (bf16)1.0f;
      for (int c = 90; c < LDP; ++c) Hl[b][i][c] = (bf16)0.f;
    }
  }

  float hold[BMn / 16][4];
#pragma unroll
  for (int mt = 0; mt < BMn / 16; ++mt)
#pragma unroll
    for (int q = 0; q < 4; ++q) hold[mt][q] = 0.f;

  // lane-constant LDS bases
  bf16*       hwb = &Hl[0][0][0] + (kg * 4) * LDP + j;          // H write base
  const bf16* xrb = &Xl[0][0][0] + l15 * LDP + kg * 8;          // A-frag read bases
  const bf16* hrb = &Hl[0][0][0] + l15 * LDP + kg * 8;
  const int bufo = BMn * LDP;

  for (int t = 0; t < Tn; ++t) {
    const int b = t & 1;
    // ---- produce into buf b ----
    if (jok) {
      bf16* hw = hwb + b * bufo;
#pragma unroll
      for (int mt = 0; mt < BMn / 16; ++mt)
#pragma unroll
        for (int q = 0; q < 4; ++q)
          hw[(mt * 16 + q) * LDP] = (bf16)hold[mt][q];
    }
#pragma unroll
    for (int i = 0; i < 8; ++i) {
      if (valid[i]) {
        bf16x2 v; v.x = (bf16)pa[i]; v.y = (bf16)pb[i];
        *(bf16x2*)(&Xl[b][0][0] + loff[i]) = v;
      }
    }
    tH += Hn;
    if (t + 1 < Tn) issue(tH);
    __syncthreads();

    // ---- consume buf b ----
    __builtin_amdgcn_s_setprio(1);
    const bf16* xr = xrb + b * bufo;
    const bf16* hr = hrb + b * bufo;
#pragma unroll
    for (int mt = 0; mt < BMn / 16; ++mt) {
      f32x4 ar = {0,0,0,0}, az = {0,0,0,0}, ain = {0,0,0,0}, ahn = {0,0,0,0};
#pragma unroll
      for (int kt = 0; kt < 3; ++kt) {
        const bf16x8 ax = *(const bf16x8*)(xr + mt * 16 * LDP + kt * 32);
        const bf16x8 ah = *(const bf16x8*)(hr + mt * 16 * LDP + kt * 32);
        ar  = __builtin_amdgcn_mfma_f32_16x16x32_bf16(ax, Bf[0][0][kt], ar, 0, 0, 0);
        ar  = __builtin_amdgcn_mfma_f32_16x16x32_bf16(ah, Bf[0][1][kt], ar, 0, 0, 0);
        az  = __builtin_amdgcn_mfma_f32_16x16x32_bf16(ax, Bf[1][0][kt], az, 0, 0, 0);
        az  = __builtin_amdgcn_mfma_f32_16x16x32_bf16(ah, Bf[1][1][kt], az, 0, 0, 0);
        ain = __builtin_amdgcn_mfma_f32_16x16x32_bf16(ax, Bf[2][0][kt], ain, 0, 0, 0);
        ahn = __builtin_amdgcn_mfma_f32_16x16x32_bf16(ah, Bf[2][1][kt], ahn, 0, 0, 0);
      }
#pragma unroll
      for (int q = 0; q < 4; ++q) {
        const float r_ = fsig(ar[q]);
        const float z_ = fsig(az[q]);
        const float n_ = ftanh(ain[q] + r_ * ahn[q]);
        const float hp = hold[mt][q];
        hold[mt][q] = n_ + z_ * (hp - n_);
      }
    }
    __builtin_amdgcn_s_setprio(0);
  }

  // ---- final h -> LDS for epilogue ----
  if (jok) {
#pragma unroll
    for (int mt = 0; mt < BMn / 16; ++mt)
#pragma unroll
      for (int q = 0; q < 4; ++q)
        hwb[(mt * 16 + q) * LDP] = (bf16)hold[mt][q];
  }
  __syncthreads();

  // ---- epilogue: metric_fc (89->32, sigmoid) then output_fc (32->1) ----
  const bf16* Hf = &Hl[0][0][0];
  for (int p = tid; p < BMn * 32; p += NTHR) {
    const int r = p >> 5, c = p & 31;
    float acc = bm[c];
    const bf16* hr2 = Hf + r * LDP;
    for (int k = 0; k < Hn; ++k) acc = fmaf((float)hr2[k], Wm[c * Hn + k], acc);
    const float mv = fsig(acc);
    Ml[r][c] = mv;
    Y[(size_t)Bt + (brow0 + r) * 32 + c] = mv;   // out_mmetric
  }
  __syncthreads();
  if (tid < BMn) {
    float acc = bo[0];
#pragma unroll
    for (int c = 0; c < 32; ++c) acc = fmaf(Ml[tid][c], Wo[c], acc);
    Y[brow0 + tid] = fsig(acc);                  // out_mscore
  }
}

extern "C" void kernel_launch(void* const* d_in, const int* in_sizes, int n_in,
                              void* d_out, int out_size, void* d_ws, size_t ws_size,
                              hipStream_t stream) {
  const float* X   = (const float*)d_in[0];
  const float* Wih = (const float*)d_in[1];
  const float* Whh = (const float*)d_in[2];
  const float* bih = (const float*)d_in[3];
  const float* bhh = (const float*)d_in[4];
  const float* Wm  = (const float*)d_in[5];
  const float* bm  = (const float*)d_in[6];
  const float* Wo  = (const float*)d_in[7];
  const float* bo  = (const float*)d_in[8];

  const int B = in_sizes[0] / (Tn * Hn);   // 32768
  dim3 grid(B / BMn), block(NTHR);
  gru_fused<<<grid, block, 0, stream>>>(X, Wih, Whh, bih, bhh, Wm, bm, Wo, bo,
                                        (float*)d_out, B);
}